// Round 1
// baseline (1461.683 us; speedup 1.0000x reference)
//
#include <hip/hip_runtime.h>
#include <hip/hip_bf16.h>

using bf16 = __hip_bfloat16;
typedef __attribute__((ext_vector_type(8))) short short8;
typedef __attribute__((ext_vector_type(4))) float f32x4;

#define MFMA(a,b,c) __builtin_amdgcn_mfma_f32_16x16x32_bf16(a, b, c, 0, 0, 0)

#define B_      128
#define C_      1024
#define NH      8
#define HD      128
#define HW      24
#define NTOK    576
#define QH      12
#define QN      144

static __device__ __forceinline__ float bf2f(bf16 v) { return __bfloat162float(v); }
static __device__ __forceinline__ bf16  f2bf(float v) { return __float2bfloat16(v); }
static __device__ __forceinline__ float s2f(short s) {
    return __uint_as_float(((unsigned)(unsigned short)s) << 16);
}

__device__ __forceinline__ void gll16(const bf16* src, bf16* dst_lds) {
    __builtin_amdgcn_global_load_lds(
        (__attribute__((address_space(1))) const unsigned int*)src,
        (__attribute__((address_space(3))) unsigned int*)dst_lds,
        16, 0, 0);
}

// ---------------- transpose + fp32->bf16 convert: out[c][r] = in[r][c] ----------------
__global__ __launch_bounds__(256) void transpose_cvt(
    const float* __restrict__ in, bf16* __restrict__ out,
    int R, int Ccols, size_t ibs, size_t obs)
{
    __shared__ float tile[32][33];
    const float* ib = in + (size_t)blockIdx.z * ibs;
    bf16* ob = out + (size_t)blockIdx.z * obs;
    int c0 = blockIdx.x * 32, r0 = blockIdx.y * 32;
    int tx = threadIdx.x & 31, ty = threadIdx.x >> 5;
    #pragma unroll
    for (int i = 0; i < 32; i += 8)
        tile[ty + i][tx] = ib[(size_t)(r0 + ty + i) * Ccols + c0 + tx];
    __syncthreads();
    #pragma unroll
    for (int i = 0; i < 32; i += 8)
        ob[(size_t)(c0 + ty + i) * R + r0 + tx] = f2bf(tile[tx][ty + i]);
}

// ---------------- 3x3 s2 avg pool (count_include_pad), xt[B*N][C] -> xp[B*qN][C] ------
__global__ __launch_bounds__(256) void pool_kernel(const bf16* __restrict__ xt,
                                                   bf16* __restrict__ xp)
{
    int bqn = blockIdx.x;
    int b = bqn / QN, qn = bqn % QN;
    int y = qn / QH, x = qn % QH;
    int t = threadIdx.x;
    float s0 = 0, s1 = 0, s2 = 0, s3 = 0;
    for (int dy = 0; dy < 3; dy++) {
        int hy = 2 * y - 1 + dy;
        if (hy < 0 || hy >= HW) continue;
        for (int dx = 0; dx < 3; dx++) {
            int hx = 2 * x - 1 + dx;
            if (hx < 0 || hx >= HW) continue;
            const bf16* row = xt + (size_t)(b * NTOK + hy * HW + hx) * C_;
            s0 += bf2f(row[t]);
            s1 += bf2f(row[t + 256]);
            s2 += bf2f(row[t + 512]);
            s3 += bf2f(row[t + 768]);
        }
    }
    bf16* o = xp + (size_t)bqn * C_;
    const float n = 1.f / 9.f;
    o[t] = f2bf(s0 * n); o[t + 256] = f2bf(s1 * n);
    o[t + 512] = f2bf(s2 * n); o[t + 768] = f2bf(s3 * n);
}

// ---------------- NT GEMM: C[m][n] = sum_k A[m][k]*Bt[n][k], K=1024 -------------------
// EPI 0: bf16 row-major [M][1024]
// EPI 1: Vt store: row=channel, col=token -> out[(b*1024+ch)*576 + n]
// EPI 2: fp32 out + bias: row=channel, col=token -> out[b*147456 + ch*144 + qn]
template<int EPI>
__global__ __launch_bounds__(256, 2) void gemm_nt(
    const bf16* __restrict__ A, const bf16* __restrict__ Bt,
    void* __restrict__ Cout, const float* __restrict__ bias)
{
    __shared__ bf16 lds[2][2][128 * 64];
    const int tid = threadIdx.x;
    const int wv = tid >> 6, ln = tid & 63;
    const int m0 = blockIdx.x * 128, n0 = blockIdx.y * 128;
    const int wr = wv >> 1, wc = wv & 1;
    const int l15 = ln & 15, l4 = ln >> 4;
    const int r8 = ln >> 3, sl = ln & 7;
    const int sg = sl ^ r8;   // pre-swizzled global slot so LDS stays linear

    const bf16* gA = A + (size_t)m0 * C_;
    const bf16* gB = Bt + (size_t)n0 * C_;

    f32x4 zero = {0.f, 0.f, 0.f, 0.f};
    f32x4 acc[4][4];
    #pragma unroll
    for (int i = 0; i < 4; i++)
        #pragma unroll
        for (int j = 0; j < 4; j++) acc[i][j] = zero;

    auto stage = [&](int kt, int d) {
        const bf16* sa = gA + kt * 64;
        const bf16* sb = gB + kt * 64;
        bf16* la = lds[d][0];
        bf16* lb = lds[d][1];
        #pragma unroll
        for (int i = 0; i < 4; i++) {
            int chunk = wv * 4 + i;
            gll16(sa + (size_t)(chunk * 8 + r8) * C_ + sg * 8, la + chunk * 512);
            gll16(sb + (size_t)(chunk * 8 + r8) * C_ + sg * 8, lb + chunk * 512);
        }
    };

    stage(0, 0);
    asm volatile("s_waitcnt vmcnt(0)");
    __syncthreads();

    int cur = 0;
    for (int kt = 0; kt < 16; kt++) {
        if (kt < 15) stage(kt + 1, cur ^ 1);
        const bf16* la = lds[cur][0];
        const bf16* lb = lds[cur][1];
        #pragma unroll
        for (int ks = 0; ks < 2; ks++) {
            short8 af[4], bfr[4];
            #pragma unroll
            for (int fm = 0; fm < 4; fm++) {
                int row = wr * 64 + fm * 16 + l15;
                int slot = (ks * 4 + l4) ^ (row & 7);
                af[fm] = *(const short8*)((const char*)la + row * 128 + slot * 16);
            }
            #pragma unroll
            for (int fn = 0; fn < 4; fn++) {
                int row = wc * 64 + fn * 16 + l15;
                int slot = (ks * 4 + l4) ^ (row & 7);
                bfr[fn] = *(const short8*)((const char*)lb + row * 128 + slot * 16);
            }
            #pragma unroll
            for (int fm = 0; fm < 4; fm++)
                #pragma unroll
                for (int fn = 0; fn < 4; fn++)
                    acc[fm][fn] = MFMA(af[fm], bfr[fn], acc[fm][fn]);
        }
        asm volatile("s_waitcnt vmcnt(0)");
        __syncthreads();
        cur ^= 1;
    }

    #pragma unroll
    for (int fm = 0; fm < 4; fm++) {
        #pragma unroll
        for (int fn = 0; fn < 4; fn++) {
            #pragma unroll
            for (int r = 0; r < 4; r++) {
                int row = m0 + wr * 64 + fm * 16 + l4 * 4 + r;
                int col = n0 + wc * 64 + fn * 16 + l15;
                float v = acc[fm][fn][r];
                if constexpr (EPI == 0) {
                    ((bf16*)Cout)[(size_t)row * C_ + col] = f2bf(v);
                } else if constexpr (EPI == 1) {
                    int bb = col / NTOK, nn = col % NTOK;
                    ((bf16*)Cout)[((size_t)bb * C_ + row) * NTOK + nn] = f2bf(v);
                } else {
                    int bb = col / QN, qn = col % QN;
                    ((float*)Cout)[(size_t)bb * (C_ * QN) + (size_t)row * QN + qn] =
                        v + bias[row];
                }
            }
        }
    }
}

// ---------------- fused pooled-Q attention, one block per (b,h), 3 waves --------------
__global__ __launch_bounds__(192) void attn_kernel(
    const bf16* __restrict__ qbuf, const bf16* __restrict__ kbuf,
    const bf16* __restrict__ vt, const float* __restrict__ rph,
    const float* __restrict__ rpw, bf16* __restrict__ attno)
{
    __shared__ float relh[3][48 * 24];
    __shared__ float relw[3][48 * 24];
    __shared__ char  plds[3][48 * 128];

    const int bh = blockIdx.x;
    const int b = bh >> 3, h = bh & 7;
    const int w = threadIdx.x >> 6, ln = threadIdx.x & 63;
    const int l15 = ln & 15, l4 = ln >> 4;

    const bf16* qbase = qbuf + ((size_t)(b * QN + w * 48) * C_ + h * HD);
    const bf16* kbase = kbuf + ((size_t)b * NTOK * C_ + h * HD);
    const bf16* vbase = vt + (size_t)(b * C_ + h * HD) * NTOK;

    // relative-position bias tables: relh[qr][kr] = q[qr] . rel_pos_h[2y-kr+23]
    for (int i = ln; i < 48 * 24; i += 64) {
        int qr = i / 24, kk = i - qr * 24;
        int qg = w * 48 + qr;
        int y = qg / 12, x = qg - y * 12;
        const short8* q8 = (const short8*)(qbuf + ((size_t)(b * QN + qg) * C_ + h * HD));
        const float* rh = rph + (2 * y - kk + 23) * HD;
        const float* rw = rpw + (2 * x - kk + 23) * HD;
        float sh = 0.f, sw = 0.f;
        for (int c0 = 0; c0 < 16; c0++) {
            short8 qv = q8[c0];
            #pragma unroll
            for (int j = 0; j < 8; j++) {
                float qf_ = s2f(qv[j]);
                sh = fmaf(qf_, rh[c0 * 8 + j], sh);
                sw = fmaf(qf_, rw[c0 * 8 + j], sw);
            }
        }
        relh[w][i] = sh;
        relw[w][i] = sw;
    }
    __syncthreads();

    // persistent q fragments (A-operand layout)
    short8 qfr[3][4];
    #pragma unroll
    for (int fq = 0; fq < 3; fq++)
        #pragma unroll
        for (int ks = 0; ks < 4; ks++)
            qfr[fq][ks] = *(const short8*)(qbase + (size_t)(fq * 16 + l15) * C_ + ks * 32 + l4 * 8);

    f32x4 zero = {0.f, 0.f, 0.f, 0.f};
    f32x4 Of[3][8];
    float mrun[3][4], lrun[3][4];
    #pragma unroll
    for (int fq = 0; fq < 3; fq++) {
        #pragma unroll
        for (int hf = 0; hf < 8; hf++) Of[fq][hf] = zero;
        #pragma unroll
        for (int r = 0; r < 4; r++) { mrun[fq][r] = -1e30f; lrun[fq][r] = 0.f; }
    }

    const float scale = 0.08838834764831845f;  // 1/sqrt(128)

    for (int kt = 0; kt < 9; kt++) {
        // S = q @ k^T (per wave: 48 x 64 tile)
        f32x4 S[3][4];
        #pragma unroll
        for (int kf = 0; kf < 4; kf++) {
            short8 bfr[4];
            #pragma unroll
            for (int ks = 0; ks < 4; ks++)
                bfr[ks] = *(const short8*)(kbase + (size_t)(kt * 64 + kf * 16 + l15) * C_ +
                                           ks * 32 + l4 * 8);
            #pragma unroll
            for (int fq = 0; fq < 3; fq++) {
                f32x4 acc = zero;
                #pragma unroll
                for (int ks = 0; ks < 4; ks++) acc = MFMA(qfr[fq][ks], bfr[ks], acc);
                S[fq][kf] = acc;
            }
        }
        // scale + rel-pos bias
        #pragma unroll
        for (int kf = 0; kf < 4; kf++) {
            int key = kt * 64 + kf * 16 + l15;
            int kr = key / 24, kc = key - kr * 24;
            #pragma unroll
            for (int fq = 0; fq < 3; fq++) {
                int qr0 = fq * 16 + l4 * 4;
                #pragma unroll
                for (int r = 0; r < 4; r++)
                    S[fq][kf][r] = S[fq][kf][r] * scale +
                                   relh[w][(qr0 + r) * 24 + kr] +
                                   relw[w][(qr0 + r) * 24 + kc];
            }
        }
        // online softmax
        float alpha[3][4];
        #pragma unroll
        for (int fq = 0; fq < 3; fq++) {
            #pragma unroll
            for (int r = 0; r < 4; r++) {
                float mt = fmaxf(fmaxf(S[fq][0][r], S[fq][1][r]),
                                 fmaxf(S[fq][2][r], S[fq][3][r]));
                #pragma unroll
                for (int d = 1; d < 16; d <<= 1) mt = fmaxf(mt, __shfl_xor(mt, d, 64));
                float mn = fmaxf(mrun[fq][r], mt);
                alpha[fq][r] = __expf(mrun[fq][r] - mn);
                mrun[fq][r] = mn;
                float ps = 0.f;
                #pragma unroll
                for (int kf = 0; kf < 4; kf++) {
                    float p = __expf(S[fq][kf][r] - mn);
                    S[fq][kf][r] = p;
                    ps += p;
                }
                #pragma unroll
                for (int d = 1; d < 16; d <<= 1) ps += __shfl_xor(ps, d, 64);
                lrun[fq][r] = lrun[fq][r] * alpha[fq][r] + ps;
            }
        }
        // rescale O
        #pragma unroll
        for (int fq = 0; fq < 3; fq++)
            #pragma unroll
            for (int hf = 0; hf < 8; hf++)
                #pragma unroll
                for (int r = 0; r < 4; r++) Of[fq][hf][r] *= alpha[fq][r];
        // P -> LDS (bf16, XOR-swizzled rows of 128B)
        #pragma unroll
        for (int fq = 0; fq < 3; fq++) {
            int row0 = fq * 16 + l4 * 4;
            #pragma unroll
            for (int kf = 0; kf < 4; kf++) {
                int key = kf * 16 + l15;
                int slotb = key >> 3, kin = key & 7;
                #pragma unroll
                for (int r = 0; r < 4; r++) {
                    int row = row0 + r;
                    int byt = row * 128 + ((slotb ^ (row & 7)) << 4) + kin * 2;
                    *(bf16*)(&plds[w][byt]) = f2bf(S[fq][kf][r]);
                }
            }
        }
        // PV: O += P @ V  (V read via Vt rows, k-contiguous)
        #pragma unroll
        for (int ks2 = 0; ks2 < 2; ks2++) {
            short8 pa[3];
            #pragma unroll
            for (int fq = 0; fq < 3; fq++) {
                int row = fq * 16 + l15;
                int slot = (ks2 * 4 + l4) ^ (row & 7);
                pa[fq] = *(const short8*)(&plds[w][row * 128 + slot * 16]);
            }
            #pragma unroll
            for (int hf = 0; hf < 8; hf++) {
                short8 vb = *(const short8*)(vbase + (size_t)(hf * 16 + l15) * NTOK +
                                             kt * 64 + ks2 * 32 + l4 * 8);
                #pragma unroll
                for (int fq = 0; fq < 3; fq++)
                    Of[fq][hf] = MFMA(pa[fq], vb, Of[fq][hf]);
            }
        }
    }

    // epilogue: O/l + q residual
    bf16* obase = attno + ((size_t)(b * QN + w * 48) * C_ + h * HD);
    #pragma unroll
    for (int fq = 0; fq < 3; fq++) {
        #pragma unroll
        for (int r = 0; r < 4; r++) {
            int qr = fq * 16 + l4 * 4 + r;
            float inv = 1.f / lrun[fq][r];
            #pragma unroll
            for (int hf = 0; hf < 8; hf++) {
                int hd = hf * 16 + l15;
                float o = Of[fq][hf][r] * inv + bf2f(qbase[(size_t)qr * C_ + hd]);
                obase[(size_t)qr * C_ + hd] = f2bf(o);
            }
        }
    }
}

extern "C" void kernel_launch(void* const* d_in, const int* in_sizes, int n_in,
                              void* d_out, int out_size, void* d_ws, size_t ws_size,
                              hipStream_t stream)
{
    const float* x   = (const float*)d_in[0];
    const float* Wq  = (const float*)d_in[1];
    const float* Wk  = (const float*)d_in[2];
    const float* Wv  = (const float*)d_in[3];
    const float* Wp  = (const float*)d_in[4];
    const float* bp  = (const float*)d_in[5];
    const float* rph = (const float*)d_in[6];
    const float* rpw = (const float*)d_in[7];

    char* ws = (char*)d_ws;
    const size_t MB = 1024 * 1024;
    bf16* Wqt  = (bf16*)(ws + 0 * MB);
    bf16* Wkt  = (bf16*)(ws + 2 * MB);
    bf16* Wvt  = (bf16*)(ws + 4 * MB);
    bf16* Wpt  = (bf16*)(ws + 6 * MB);
    bf16* xt   = (bf16*)(ws + 8 * MB);          // 144 MB, reused as attno
    bf16* kbuf = (bf16*)(ws + 152 * MB);        // 144 MB
    bf16* vtb  = (bf16*)(ws + 296 * MB);        // 144 MB
    bf16* xp   = (bf16*)(ws + 440 * MB);        // 36 MB
    bf16* qbuf = (bf16*)(ws + 476 * MB);        // 36 MB -> end 512 MB
    bf16* attno = xt;

    // weights: [K][N] fp32 -> [N][K] bf16
    transpose_cvt<<<dim3(32, 32, 1), 256, 0, stream>>>(Wq, Wqt, 1024, 1024, 0, 0);
    transpose_cvt<<<dim3(32, 32, 1), 256, 0, stream>>>(Wk, Wkt, 1024, 1024, 0, 0);
    transpose_cvt<<<dim3(32, 32, 1), 256, 0, stream>>>(Wv, Wvt, 1024, 1024, 0, 0);
    transpose_cvt<<<dim3(32, 32, 1), 256, 0, stream>>>(Wp, Wpt, 1024, 1024, 0, 0);
    // x: [B][C][576] fp32 -> xt [B*576][C] bf16
    transpose_cvt<<<dim3(18, 32, 128), 256, 0, stream>>>(
        x, xt, 1024, 576, (size_t)1024 * 576, (size_t)576 * 1024);
    // pooled q input
    pool_kernel<<<dim3(B_ * QN), 256, 0, stream>>>(xt, xp);
    // projections
    gemm_nt<0><<<dim3(576, 8), 256, 0, stream>>>(xt, Wkt, kbuf, nullptr);
    gemm_nt<1><<<dim3(8, 576), 256, 0, stream>>>(Wvt, xt, vtb, nullptr);
    gemm_nt<0><<<dim3(144, 8), 256, 0, stream>>>(xp, Wqt, qbuf, nullptr);
    // attention
    attn_kernel<<<dim3(B_ * NH), 192, 0, stream>>>(qbuf, kbuf, vtb, rph, rpw, attno);
    // output projection (+bias), stored as [B][C][12][12] fp32
    gemm_nt<2><<<dim3(8, 144), 256, 0, stream>>>(Wpt, attno, d_out, bp);
}